// Round 1
// baseline (29.266 us; speedup 1.0000x reference)
//
#include <hip/hip_runtime.h>

#define H 512
#define W 512
#define KH 9
#define KW 9
#define PAD 4
#define BX 16
#define BY 16
#define TS (BX + KW - 1)  // 24

__device__ __forceinline__ int reflect_idx(int p, int n) {
    // jnp.pad mode="reflect": edge not repeated; pad (4) < n (512) so one fold suffices
    if (p < 0) p = -p;
    if (p >= n) p = 2 * n - 2 - p;
    return p;
}

__global__ __launch_bounds__(BX * BY) void svblur_kernel(
    const float* __restrict__ x,
    const float* __restrict__ kf,
    float* __restrict__ out)
{
    __shared__ float xs[3][TS][TS];

    const int tx = threadIdx.x;
    const int ty = threadIdx.y;
    const int tid = ty * BX + tx;
    const int w0 = blockIdx.x * BX;
    const int h0 = blockIdx.y * BY;

    // Cooperative load of the (TS x TS) halo tile for all 3 channels,
    // reflect padding applied at load time.
    for (int idx = tid; idx < TS * TS; idx += BX * BY) {
        int r = idx / TS;
        int c = idx - r * TS;
        int gh = reflect_idx(h0 - PAD + r, H);
        int gw = reflect_idx(w0 - PAD + c, W);
        int g = gh * W + gw;
        xs[0][r][c] = x[g];
        xs[1][r][c] = x[H * W + g];
        xs[2][r][c] = x[2 * H * W + g];
    }
    __syncthreads();

    const int h = h0 + ty;
    const int w = w0 + tx;
    const float* kp = kf + (size_t)(h * W + w) * (KH * KW);

    float a0 = 0.f, a1 = 0.f, a2 = 0.f;
#pragma unroll
    for (int i = 0; i < KH; ++i) {
#pragma unroll
        for (int j = 0; j < KW; ++j) {
            float wgt = kp[i * KW + j];
            a0 += xs[0][ty + i][tx + j] * wgt;
            a1 += xs[1][ty + i][tx + j] * wgt;
            a2 += xs[2][ty + i][tx + j] * wgt;
        }
    }

    const int o = h * W + w;
    out[o] = a0;
    out[H * W + o] = a1;
    out[2 * H * W + o] = a2;
}

extern "C" void kernel_launch(void* const* d_in, const int* in_sizes, int n_in,
                              void* d_out, int out_size, void* d_ws, size_t ws_size,
                              hipStream_t stream) {
    const float* x  = (const float*)d_in[0];
    const float* kf = (const float*)d_in[1];
    float* out = (float*)d_out;

    dim3 block(BX, BY);
    dim3 grid(W / BX, H / BY);
    svblur_kernel<<<grid, block, 0, stream>>>(x, kf, out);
}

// Round 2
// 28.291 us; speedup vs baseline: 1.0345x; 1.0345x over previous
//
#include <hip/hip_runtime.h>
#include <stdint.h>

#define H 512
#define W 512
#define KT 81        // 9x9 taps per pixel
#define PAD 4
#define SEGW 64      // output pixels per (1-wave) block
#define TSW (SEGW + 2 * PAD)   // 72 halo columns
#define XROWS 9                // halo rows
#define XDWORDS (3 * XROWS * TSW)  // 1944 dwords of x halo

typedef const __attribute__((address_space(1))) void* gptr1_t;
typedef __attribute__((address_space(3))) void* lptr3_t;

__device__ __forceinline__ int reflect_idx(int p) {
    // jnp.pad mode="reflect", pad=4 < 512 so one fold suffices
    if (p < 0) p = -p;
    if (p >= H) p = 2 * H - 2 - p;
    return p;
}

__global__ __launch_bounds__(64) void svblur_kernel(
    const float* __restrict__ x,
    const float* __restrict__ kf,
    float* __restrict__ out)
{
    __shared__ float wlds[SEGW * KT];          // 20736 B, pixel-major (same as global)
    __shared__ float xlds[3][XROWS][TSW];      // 7776 B

    const int lane = (int)threadIdx.x;
    const int bid = (int)blockIdx.x;
    const int h  = bid >> 3;          // 512 rows
    const int w0 = (bid & 7) * SEGW;  // 8 segments per row

    // ---- Stage weights: 64 px * 81 dwords = 20736 B, fully contiguous.
    // 20 full wave-wide 1KB copies + one 256B tail (16 lanes).
    {
        const uint32_t* wsrc = (const uint32_t*)(kf + (size_t)(h * W + w0) * KT);
        char* wbase = (char*)&wlds[0];
#pragma unroll
        for (int it = 0; it < 20; ++it) {
            __builtin_amdgcn_global_load_lds(
                (gptr1_t)(wsrc + it * 256 + lane * 4),
                (lptr3_t)(wbase + it * 1024),
                16, 0, 0);
        }
        if (lane < 16) {
            __builtin_amdgcn_global_load_lds(
                (gptr1_t)(wsrc + 20 * 256 + lane * 4),
                (lptr3_t)(wbase + 20 * 1024),
                16, 0, 0);
        }
    }

    // ---- Stage x halo: 3 ch * 9 rows * 72 cols = 1944 dwords, reflect on the
    // per-lane GLOBAL address (LDS dest stays linear: wave-uniform base + lane*4).
    {
        const uint32_t* xsrc = (const uint32_t*)x;
        char* xbase = (char*)&xlds[0][0][0];
#pragma unroll
        for (int it = 0; it < 31; ++it) {   // 31*64 = 1984 >= 1944
            int idx = it * 64 + lane;
            if (idx < XDWORDS) {
                int c   = idx / (XROWS * TSW);
                int rem = idx - c * (XROWS * TSW);
                int r   = rem / TSW;
                int col = rem - r * TSW;
                int gh = reflect_idx(h - PAD + r);
                int gw = reflect_idx(w0 - PAD + col);
                __builtin_amdgcn_global_load_lds(
                    (gptr1_t)(xsrc + (size_t)c * H * W + gh * W + gw),
                    (lptr3_t)(xbase + it * 256),
                    4, 0, 0);
            }
        }
    }

    __syncthreads();   // drains vmcnt for all global_load_lds before LDS reads

    // ---- Compute: weight reads stride 81 dwords across lanes (gcd(81,32)=1,
    // conflict-free); x reads stride 1 (conflict-free).
    const float* wp = &wlds[lane * KT];
    float a0 = 0.f, a1 = 0.f, a2 = 0.f;
#pragma unroll
    for (int i = 0; i < 9; ++i) {
#pragma unroll
        for (int j = 0; j < 9; ++j) {
            float wv = wp[i * 9 + j];
            a0 += xlds[0][i][lane + j] * wv;
            a1 += xlds[1][i][lane + j] * wv;
            a2 += xlds[2][i][lane + j] * wv;
        }
    }

    const int o = h * W + w0 + lane;
    out[o] = a0;
    out[H * W + o] = a1;
    out[2 * H * W + o] = a2;
}

extern "C" void kernel_launch(void* const* d_in, const int* in_sizes, int n_in,
                              void* d_out, int out_size, void* d_ws, size_t ws_size,
                              hipStream_t stream) {
    const float* x  = (const float*)d_in[0];
    const float* kf = (const float*)d_in[1];
    float* out = (float*)d_out;

    dim3 block(64);
    dim3 grid(H * (W / SEGW));   // 512 rows * 8 segments = 4096 one-wave blocks
    svblur_kernel<<<grid, block, 0, stream>>>(x, kf, out);
}

// Round 3
// 26.656 us; speedup vs baseline: 1.0979x; 1.0613x over previous
//
#include <hip/hip_runtime.h>
#include <stdint.h>

#define H 512
#define W 512
#define HW (H * W)
#define KT 81     // 9x9 taps per pixel
#define PAD 4

__device__ __forceinline__ int reflect_idx(int p) {
    // jnp.pad mode="reflect": pad (4) < 512, one fold suffices
    if (p < 0) p = -p;
    if (p >= H) p = 2 * H - 2 - p;
    return p;
}

__global__ __launch_bounds__(64) void svblur_kernel(
    const float* __restrict__ x,
    const float* __restrict__ kf,
    float* __restrict__ out)
{
    __shared__ float wlds[64 * KT];   // 20736 B

    const int l   = (int)threadIdx.x;
    const int bid = (int)blockIdx.x;
    const int h   = bid >> 3;          // 512 rows
    const int w0  = (bid & 7) << 6;    // 8 segments of 64 px per row

    // ---- Stage weights for the 64 pixels: 5184 contiguous dwords.
    // Coalesced dwordx4 loads -> regs -> ds_write_b128 (16B-aligned: the
    // segment's dword base (h*512+w0)*81 is divisible by 4). The per-lane
    // transposed view is read back below via ds_read (stride 81 dwords:
    // bank = (17*l + t) mod 32 is a permutation -> conflict-free).
    {
        const float4* ws = (const float4*)(kf + ((size_t)h * W + w0) * KT);
        float4* wd = (float4*)wlds;
#pragma unroll
        for (int it = 0; it < 20; ++it)
            wd[it * 64 + l] = ws[it * 64 + l];
        if (l < 16)
            wd[20 * 64 + l] = ws[20 * 64 + l];
    }
    // single wave per block: ds_write -> ds_read ordering is enforced by
    // same-wave lgkmcnt; no barrier needed.

    // ---- Reflected column offsets, computed once, reused as the v-offset
    // of every x load (zero per-load address VALU).
    int rgw[9];
#pragma unroll
    for (int j = 0; j < 9; ++j)
        rgw[j] = reflect_idx(w0 - PAD + l + j);

    const float* wp = wlds + l * KT;
    float a0 = 0.f, a1 = 0.f, a2 = 0.f;

#pragma unroll
    for (int i = 0; i < 9; ++i) {
        const int gh = reflect_idx(h - PAD + i);
        const float* r0 = x + (size_t)gh * W;   // channel 0 row
        const float* r1 = r0 + HW;
        const float* r2 = r1 + HW;

        // direct global loads: lane-contiguous per (c,i,j) -> fully coalesced,
        // band window (~8KB) stays L1-resident across the 9 tap rows.
        float xv0[9], xv1[9], xv2[9];
#pragma unroll
        for (int j = 0; j < 9; ++j) {
            xv0[j] = r0[rgw[j]];
            xv1[j] = r1[rgw[j]];
            xv2[j] = r2[rgw[j]];
        }

#pragma unroll
        for (int j = 0; j < 9; ++j) {
            const float wv = wp[i * 9 + j];
            a0 = fmaf(xv0[j], wv, a0);
            a1 = fmaf(xv1[j], wv, a1);
            a2 = fmaf(xv2[j], wv, a2);
        }
    }

    const int o = h * W + w0 + l;
    out[o]          = a0;
    out[o + HW]     = a1;
    out[o + 2 * HW] = a2;
}

extern "C" void kernel_launch(void* const* d_in, const int* in_sizes, int n_in,
                              void* d_out, int out_size, void* d_ws, size_t ws_size,
                              hipStream_t stream) {
    const float* x  = (const float*)d_in[0];
    const float* kf = (const float*)d_in[1];
    float* out = (float*)d_out;

    dim3 block(64);
    dim3 grid(H * (W / 64));   // 4096 one-wave blocks
    svblur_kernel<<<grid, block, 0, stream>>>(x, kf, out);
}

// Round 4
// 24.236 us; speedup vs baseline: 1.2076x; 1.0999x over previous
//
#include <hip/hip_runtime.h>
#include <stdint.h>

#define H 512
#define W 512
#define HW (H * W)
#define KT 81     // 9x9 taps per pixel
#define PAD 4
#define SEGW 64   // pixels per block (one row segment)

__device__ __forceinline__ int reflect_idx(int p) {
    // jnp.pad mode="reflect": pad (4) < 512, one fold suffices
    if (p < 0) p = -p;
    if (p >= H) p = 2 * H - 2 - p;
    return p;
}

// 192 threads = 3 waves; wave c computes channel c of a 64-pixel row segment.
// Weights for the 64 pixels (20736 B, contiguous) are staged once into LDS by
// all 3 waves cooperatively, then read back per-lane at dword stride 81
// (bank = (17*l + t) mod 32 is a permutation -> conflict-free).
__global__ __launch_bounds__(192) void svblur_kernel(
    const float* __restrict__ x,
    const float* __restrict__ kf,
    float* __restrict__ out)
{
    __shared__ float wlds[SEGW * KT];   // 20736 B -> 7 blocks/CU (21 waves)

    const int tid = (int)threadIdx.x;
    const int l   = tid & 63;           // lane within wave = pixel in segment
    const int wv  = tid >> 6;           // wave id = channel (0..2)
    const int bid = (int)blockIdx.x;
    const int h   = bid >> 3;           // 512 rows
    const int w0  = (bid & 7) << 6;     // 8 segments of 64 px per row

    // ---- Stage weights: 5184 dwords = 1296 float4, 21 wave-ops split 7/wave.
    {
        const float4* ws = (const float4*)(kf + ((size_t)h * W + w0) * KT);
        float4* wd = (float4*)wlds;
#pragma unroll
        for (int it = 0; it < 7; ++it) {
            int idx = (wv * 7 + it) * 64 + l;
            if (idx < (SEGW * KT) / 4)
                wd[idx] = ws[idx];
        }
    }
    __syncthreads();

    // Reflected column offsets, computed once, reused for all 81 x loads.
    int rgw[9];
#pragma unroll
    for (int j = 0; j < 9; ++j)
        rgw[j] = reflect_idx(w0 - PAD + l + j);

    const float* xc = x + (size_t)wv * HW;   // this wave's channel plane
    const float* wp = wlds + l * KT;

    float acc = 0.f;
#pragma unroll
    for (int i = 0; i < 9; ++i) {
        const int gh = reflect_idx(h - PAD + i);
        const float* row = xc + (size_t)gh * W;

        float xv[9];
#pragma unroll
        for (int j = 0; j < 9; ++j)
            xv[j] = row[rgw[j]];           // coalesced, L1-resident band

#pragma unroll
        for (int j = 0; j < 9; ++j)
            acc = fmaf(xv[j], wp[i * 9 + j], acc);
    }

    out[(size_t)wv * HW + h * W + w0 + l] = acc;
}

extern "C" void kernel_launch(void* const* d_in, const int* in_sizes, int n_in,
                              void* d_out, int out_size, void* d_ws, size_t ws_size,
                              hipStream_t stream) {
    const float* x  = (const float*)d_in[0];
    const float* kf = (const float*)d_in[1];
    float* out = (float*)d_out;

    dim3 block(192);
    dim3 grid(H * (W / SEGW));   // 4096 blocks x 3 waves = 12288 waves
    svblur_kernel<<<grid, block, 0, stream>>>(x, kf, out);
}